// Round 1
// 1128.587 us; speedup vs baseline: 1.1770x; 1.1770x over previous
//
#include <hip/hip_runtime.h>
#include <hip/hip_bf16.h>

typedef unsigned short u16;
typedef unsigned int   u32;
typedef __attribute__((ext_vector_type(8))) short short8;   // 8 bf16 (4 VGPRs)
typedef __attribute__((ext_vector_type(4))) float f32x4;

#define BBt 128
#define SS 128
#define RR 32
#define NEx 3
#define MB (1024 * 1024)

static __device__ __forceinline__ float bs2f(u16 u){ return __uint_as_float(((u32)u) << 16); }
static __device__ __forceinline__ u16 f2bs(float x){
    u32 u = __float_as_uint(x);
    u += 0x7fff + ((u >> 16) & 1);          // RNE
    return (u16)(u >> 16);
}
static __device__ __forceinline__ float ldany(const float* p){ return *p; }
static __device__ __forceinline__ float ldany(const u16* p){ return bs2f(*p); }

// ===========================================================================
// MFMA GEMM: C[M,N] = A[M,K] @ W[K,N] (+bias) (+Res).
// BM=128, BN=128 (cols >= Ncols masked), BK=32, 256 threads (4 waves 2x2).
// A: fp32 or bf16. W: fp32 row-major (transposed to LDS). C: fp32 or bf16.
// M % 128 == 0 (grid covers), K % 32 == 0, Ncols % 8 == 0. Batched via z.
// ===========================================================================
template<typename TA, typename TRes, typename TC>
__global__ __launch_bounds__(256) void gemm_mfma(
    const TA* __restrict__ A, int lda, long long sA,
    const float* __restrict__ W, int ldw, long long sW,
    const float* __restrict__ bias,
    const TRes* __restrict__ Res, int ldr,
    TC* __restrict__ C, int ldc, long long sC,
    int K, int Ncols)
{
    int bz = blockIdx.z;
    A += (long long)bz * sA;
    W += (long long)bz * sW;
    C += (long long)bz * sC;

    __shared__ __align__(16) u16 As[128][40];   // [m][k]
    __shared__ __align__(16) u16 Bs[128][40];   // [n][k] (W transposed)

    int tid = threadIdx.x;
    long long row0 = (long long)blockIdx.y * 128;
    int col0 = blockIdx.x * 128;

    int wid = tid >> 6, lane = tid & 63;
    int wm = (wid >> 1) * 64, wn = (wid & 1) * 64;
    int l15 = lane & 15, quad = lane >> 4;

    f32x4 acc[4][4];
    #pragma unroll
    for (int i = 0; i < 4; ++i)
        #pragma unroll
        for (int j = 0; j < 4; ++j)
            acc[i][j] = (f32x4){0.f, 0.f, 0.f, 0.f};

    int ar = tid >> 1, ak = (tid & 1) * 16;
    int bk0 = (tid & 15) * 2, bn0 = (tid >> 4) * 8;

    for (int kt = 0; kt < K; kt += 32) {
        {   // ---- stage A tile [128,32] -> bf16 ----
            const TA* src = A + (row0 + ar) * lda + kt + ak;
            if constexpr (sizeof(TA) == 4) {
                u16 tmp[16];
                #pragma unroll
                for (int t = 0; t < 16; t += 4) {
                    float4 f = *(const float4*)(src + t);
                    tmp[t] = f2bs(f.x); tmp[t+1] = f2bs(f.y);
                    tmp[t+2] = f2bs(f.z); tmp[t+3] = f2bs(f.w);
                }
                *(uint4*)&As[ar][ak]     = *(const uint4*)&tmp[0];
                *(uint4*)&As[ar][ak + 8] = *(const uint4*)&tmp[8];
            } else {
                *(uint4*)&As[ar][ak]     = *(const uint4*)(src);
                *(uint4*)&As[ar][ak + 8] = *(const uint4*)(src + 8);
            }
        }
        {   // ---- stage W tile [32,128] transposed -> Bs[n][k], N-guarded ----
            if (col0 + bn0 < Ncols) {
                const float* w0 = W + (long long)(kt + bk0) * ldw + col0 + bn0;
                const float* w1 = w0 + ldw;
                float r0[8], r1[8];
                *(float4*)&r0[0] = *(const float4*)(w0);
                *(float4*)&r0[4] = *(const float4*)(w0 + 4);
                *(float4*)&r1[0] = *(const float4*)(w1);
                *(float4*)&r1[4] = *(const float4*)(w1 + 4);
                #pragma unroll
                for (int i = 0; i < 8; ++i) {
                    u32 packed = (u32)f2bs(r0[i]) | ((u32)f2bs(r1[i]) << 16);
                    *(u32*)&Bs[bn0 + i][bk0] = packed;
                }
            } else {
                #pragma unroll
                for (int i = 0; i < 8; ++i)
                    *(u32*)&Bs[bn0 + i][bk0] = 0u;
            }
        }
        __syncthreads();

        short8 af[4], bfr[4];
        #pragma unroll
        for (int mt = 0; mt < 4; ++mt)
            af[mt] = *(const short8*)&As[wm + mt * 16 + l15][quad * 8];
        #pragma unroll
        for (int nt = 0; nt < 4; ++nt)
            bfr[nt] = *(const short8*)&Bs[wn + nt * 16 + l15][quad * 8];
        #pragma unroll
        for (int mt = 0; mt < 4; ++mt)
            #pragma unroll
            for (int nt = 0; nt < 4; ++nt)
                acc[mt][nt] = __builtin_amdgcn_mfma_f32_16x16x32_bf16(
                    af[mt], bfr[nt], acc[mt][nt], 0, 0, 0);
        __syncthreads();
    }

    // ---- epilogue: C/D layout col=lane&15, row=quad*4+reg ----
    #pragma unroll
    for (int mt = 0; mt < 4; ++mt) {
        #pragma unroll
        for (int r = 0; r < 4; ++r) {
            long long row = row0 + wm + mt * 16 + quad * 4 + r;
            #pragma unroll
            for (int nt = 0; nt < 4; ++nt) {
                int col = col0 + wn + nt * 16 + l15;
                if (col >= Ncols) continue;
                float v = acc[mt][nt][r];
                if (bias) v += bias[col];
                if (Res)  v += ldany(&Res[row * ldr + col]);
                if constexpr (sizeof(TC) == 4) C[row * ldc + col] = v;
                else                           C[row * ldc + col] = f2bs(v);
            }
        }
    }
}

// ===========================================================================
// Flash attention, bf16 in/out. Block per (head,batch), thread per query.
// out may alias Q (all global reads precede the post-barrier stores).
// ===========================================================================
__global__ __launch_bounds__(128) void attn_bf_k(
    const u16* __restrict__ Q, const u16* __restrict__ K,
    const u16* __restrict__ V, u16* __restrict__ out,
    int L, int causal)
{
    int h = blockIdx.x, b = blockIdx.y;
    int tid = threadIdx.x;
    __shared__ __align__(16) u16 kS[128][64];
    __shared__ __align__(16) u16 vS[128][64];

    for (int r = tid; r < L; r += 128) {
        const uint4* ks = (const uint4*)&K[((long long)b * L + r) * 512 + h * 64];
        const uint4* vs = (const uint4*)&V[((long long)b * L + r) * 512 + h * 64];
        uint4* kd = (uint4*)&kS[r][0];
        uint4* vd = (uint4*)&vS[r][0];
        #pragma unroll
        for (int t = 0; t < 8; ++t) { kd[t] = ks[t]; vd[t] = vs[t]; }
    }
    float q[64];
    {
        const u32* qp = (const u32*)&Q[((long long)b * 128 + tid) * 512 + h * 64];
        #pragma unroll
        for (int t = 0; t < 32; ++t) {
            u32 u = qp[t];
            q[2*t]   = __uint_as_float(u << 16) * 0.125f;
            q[2*t+1] = __uint_as_float(u & 0xffff0000u) * 0.125f;
        }
    }
    __syncthreads();

    int jmax = causal ? tid : (L - 1);
    float m = -1e30f, l = 0.f;
    float acc[64];
    #pragma unroll
    for (int d = 0; d < 64; ++d) acc[d] = 0.f;

    for (int j = 0; j <= jmax; ++j) {
        const uint4* kr = (const uint4*)&kS[j][0];
        float s = 0.f;
        #pragma unroll
        for (int t = 0; t < 8; ++t) {
            uint4 u4 = kr[t];
            u32 uu[4] = {u4.x, u4.y, u4.z, u4.w};
            #pragma unroll
            for (int e = 0; e < 4; ++e) {
                int d = t * 8 + e * 2;
                s = fmaf(q[d],   __uint_as_float(uu[e] << 16), s);
                s = fmaf(q[d+1], __uint_as_float(uu[e] & 0xffff0000u), s);
            }
        }
        float mn = fmaxf(m, s);
        float corr = __expf(m - mn);
        float p = __expf(s - mn);
        l = l * corr + p;
        const uint4* vr = (const uint4*)&vS[j][0];
        #pragma unroll
        for (int t = 0; t < 8; ++t) {
            uint4 u4 = vr[t];
            u32 uu[4] = {u4.x, u4.y, u4.z, u4.w};
            #pragma unroll
            for (int e = 0; e < 4; ++e) {
                int d = t * 8 + e * 2;
                acc[d]   = fmaf(p, __uint_as_float(uu[e] << 16),        acc[d]   * corr);
                acc[d+1] = fmaf(p, __uint_as_float(uu[e] & 0xffff0000u), acc[d+1] * corr);
            }
        }
        m = mn;
    }
    float inv = 1.f / l;
    u32 ou[32];
    #pragma unroll
    for (int t = 0; t < 32; ++t)
        ou[t] = (u32)f2bs(acc[2*t] * inv) | ((u32)f2bs(acc[2*t+1] * inv) << 16);
    uint4* op = (uint4*)&out[((long long)b * 128 + tid) * 512 + h * 64];
    #pragma unroll
    for (int t = 0; t < 8; ++t) op[t] = *(const uint4*)&ou[t * 4];
}

// ===========================================================================
// LayerNorm over 512, templated dtypes. In-place OK.
// ===========================================================================
template<typename TI, typename TO>
__global__ __launch_bounds__(256) void ln512_t(
    const TI* __restrict__ x, const float* __restrict__ g,
    const float* __restrict__ bt, TO* __restrict__ y, float eps)
{
    int row = blockIdx.x, tid = threadIdx.x;
    long long base = (long long)row * 512;
    float v0 = ldany(&x[base + tid]);
    float v1 = ldany(&x[base + 256 + tid]);
    float s = v0 + v1, ss = v0 * v0 + v1 * v1;
    #pragma unroll
    for (int o = 32; o >= 1; o >>= 1) { s += __shfl_xor(s, o); ss += __shfl_xor(ss, o); }
    __shared__ float red[2][4];
    int wave = tid >> 6, lane = tid & 63;
    if (lane == 0) { red[0][wave] = s; red[1][wave] = ss; }
    __syncthreads();
    s  = red[0][0] + red[0][1] + red[0][2] + red[0][3];
    ss = red[1][0] + red[1][1] + red[1][2] + red[1][3];
    float mean = s * (1.f / 512.f);
    float var = ss * (1.f / 512.f) - mean * mean;
    float rstd = rsqrtf(fmaxf(var, 0.f) + eps);
    float o0 = (v0 - mean) * rstd * g[tid]       + bt[tid];
    float o1 = (v1 - mean) * rstd * g[256 + tid] + bt[256 + tid];
    if constexpr (sizeof(TO) == 4) { y[base + tid] = o0; y[base + 256 + tid] = o1; }
    else { y[base + tid] = f2bs(o0); y[base + 256 + tid] = f2bs(o1); }
}

// ===========================================================================
// MoE expert attention v4: block = (expert e, batch b), thread = query s.
// Reads pre-projected q_e [3,16384,64]; K/V fp32 staged to LDS (broadcast
// reads, conflict-free). Two-pass softmax over R=32 entirely in registers.
// Fuses the gate: writes geo[row, e*64+d] = gate_e(row) * eo_e[row,d], so the
// gated combine collapses into ONE gemm: priori = geo[16384,192] @ Wo_cat,
// where Wo_cat is Wo_e [3,64,64] flattened row-major (= [192,64]).
// ===========================================================================
__global__ __launch_bounds__(128) void moe_attn_k(
    const float* __restrict__ qe,   // [3, B*S, 64]
    const float* __restrict__ ke,   // [3, B*R, 64]
    const float* __restrict__ ve,   // [3, B*R, 64]
    const float* __restrict__ xs,   // [B*S, 64] (for the gate)
    const float* __restrict__ Wg,   // [64,3]
    const float* __restrict__ bg,   // [3]
    float* __restrict__ geo)        // [B*S, 192]
{
    int e = blockIdx.x, b = blockIdx.y;
    int tid = threadIdx.x;
    __shared__ __align__(16) float kS[RR][64];
    __shared__ __align__(16) float vS[RR][64];

    {   // stage K/V tile for (e,b): 2048 floats each = 512 float4, coalesced
        const float4* ks = (const float4*)&ke[((long long)e * (BBt * RR) + (long long)b * RR) * 64];
        const float4* vs = (const float4*)&ve[((long long)e * (BBt * RR) + (long long)b * RR) * 64];
        float4* kd = (float4*)&kS[0][0];
        float4* vd = (float4*)&vS[0][0];
        #pragma unroll
        for (int t = 0; t < 4; ++t) {
            kd[tid + 128 * t] = ks[tid + 128 * t];
            vd[tid + 128 * t] = vs[tid + 128 * t];
        }
    }

    long long row = (long long)b * SS + tid;
    float q[64];
    {
        const float4* qp = (const float4*)&qe[((long long)e * (BBt * SS) + row) * 64];
        #pragma unroll
        for (int t = 0; t < 16; ++t) {
            float4 f = qp[t];
            q[4*t] = f.x; q[4*t+1] = f.y; q[4*t+2] = f.z; q[4*t+3] = f.w;
        }
    }

    // gate = softmax(xs_row @ Wg + bg)[e]
    float l0 = bg[0], l1 = bg[1], l2 = bg[2];
    {
        const float4* xr = (const float4*)&xs[row * 64];
        #pragma unroll
        for (int t = 0; t < 16; ++t) {
            float4 f = xr[t];
            float xv[4] = {f.x, f.y, f.z, f.w};
            #pragma unroll
            for (int u = 0; u < 4; ++u) {
                int j = 4 * t + u;
                l0 = fmaf(xv[u], Wg[j * 3 + 0], l0);
                l1 = fmaf(xv[u], Wg[j * 3 + 1], l1);
                l2 = fmaf(xv[u], Wg[j * 3 + 2], l2);
            }
        }
    }
    float mg = fmaxf(l0, fmaxf(l1, l2));
    float g0 = __expf(l0 - mg), g1 = __expf(l1 - mg), g2 = __expf(l2 - mg);
    float gate = (e == 0 ? g0 : (e == 1 ? g1 : g2)) / (g0 + g1 + g2);

    __syncthreads();

    // scores (two-pass softmax, all in registers)
    float s[RR];
    #pragma unroll
    for (int r = 0; r < RR; ++r) {
        float a0 = 0.f, a1 = 0.f, a2 = 0.f, a3 = 0.f;
        const float4* kr = (const float4*)&kS[r][0];
        #pragma unroll
        for (int t = 0; t < 16; ++t) {
            float4 f = kr[t];
            a0 = fmaf(q[4*t],   f.x, a0);
            a1 = fmaf(q[4*t+1], f.y, a1);
            a2 = fmaf(q[4*t+2], f.z, a2);
            a3 = fmaf(q[4*t+3], f.w, a3);
        }
        s[r] = ((a0 + a1) + (a2 + a3)) * 0.125f;   // 1/sqrt(64)
    }
    float m = s[0];
    #pragma unroll
    for (int r = 1; r < RR; ++r) m = fmaxf(m, s[r]);
    float l = 0.f;
    #pragma unroll
    for (int r = 0; r < RR; ++r) { s[r] = __expf(s[r] - m); l += s[r]; }
    float scale = gate / l;

    // PV
    float acc[64];
    #pragma unroll
    for (int d = 0; d < 64; ++d) acc[d] = 0.f;
    #pragma unroll
    for (int r = 0; r < RR; ++r) {
        float p = s[r];
        const float4* vr = (const float4*)&vS[r][0];
        #pragma unroll
        for (int t = 0; t < 16; ++t) {
            float4 f = vr[t];
            acc[4*t]   = fmaf(p, f.x, acc[4*t]);
            acc[4*t+1] = fmaf(p, f.y, acc[4*t+1]);
            acc[4*t+2] = fmaf(p, f.z, acc[4*t+2]);
            acc[4*t+3] = fmaf(p, f.w, acc[4*t+3]);
        }
    }
    float4* op = (float4*)&geo[row * 192 + e * 64];
    #pragma unroll
    for (int t = 0; t < 16; ++t) {
        float4 f;
        f.x = acc[4*t] * scale;   f.y = acc[4*t+1] * scale;
        f.z = acc[4*t+2] * scale; f.w = acc[4*t+3] * scale;
        op[t] = f;
    }
}

// ===========================================================================
// Small causal MHA on 64-dim priori (H=8, dh=8, S=128). qkv packed [B*S,192].
// ===========================================================================
__global__ __launch_bounds__(128) void attn_small_k(
    const float* __restrict__ qkv, float* __restrict__ out)
{
    int h = blockIdx.x, b = blockIdx.y;
    int tid = threadIdx.x;
    __shared__ float kS[SS][9], vS[SS][9];
    long long base = ((long long)b * SS + tid) * 192;
    #pragma unroll
    for (int d = 0; d < 8; ++d) {
        kS[tid][d] = qkv[base + 64 + h * 8 + d];
        vS[tid][d] = qkv[base + 128 + h * 8 + d];
    }
    float q[8];
    #pragma unroll
    for (int d = 0; d < 8; ++d)
        q[d] = qkv[base + h * 8 + d] * 0.35355339059327373f;
    __syncthreads();

    float m = -1e30f, l = 0.f, acc[8] = {};
    for (int j = 0; j <= tid; ++j) {
        float s = 0.f;
        #pragma unroll
        for (int d = 0; d < 8; ++d) s = fmaf(q[d], kS[j][d], s);
        float mn = fmaxf(m, s);
        float corr = __expf(m - mn);
        float p = __expf(s - mn);
        l = l * corr + p;
        #pragma unroll
        for (int d = 0; d < 8; ++d) acc[d] = fmaf(p, vS[j][d], acc[d] * corr);
        m = mn;
    }
    float inv = 1.f / l;
    #pragma unroll
    for (int d = 0; d < 8; ++d)
        out[((long long)b * SS + tid) * 64 + h * 8 + d] = acc[d] * inv;
}

__global__ __launch_bounds__(256) void ln64_k(
    const float* __restrict__ x, const float* __restrict__ g,
    const float* __restrict__ bt, float* __restrict__ y, int M)
{
    int wave = threadIdx.x >> 6, lane = threadIdx.x & 63;
    int row = blockIdx.x * 4 + wave;
    if (row >= M) return;
    long long base = (long long)row * 64;
    float v = x[base + lane];
    float s = v, ss = v * v;
    #pragma unroll
    for (int o = 32; o >= 1; o >>= 1) { s += __shfl_xor(s, o); ss += __shfl_xor(ss, o); }
    float mean = s * (1.f / 64.f);
    float var = ss * (1.f / 64.f) - mean * mean;
    float rstd = rsqrtf(fmaxf(var, 0.f) + 1e-5f);
    y[base + lane] = (v - mean) * rstd * g[lane] + bt[lane];
}

// ===========================================================================
extern "C" void kernel_launch(void* const* d_in, const int* in_sizes, int n_in,
                              void* d_out, int out_size, void* d_ws, size_t ws_size,
                              hipStream_t stream)
{
    (void)in_sizes; (void)n_in; (void)out_size; (void)ws_size;
    const float* hidden = (const float*)d_in[0];
    const float* tag    = (const float*)d_in[1];
    const float* feats  = (const float*)d_in[2];
    const float* refs   = (const float*)d_in[3];
    const float* W_moe  = (const float*)d_in[4];
    const float* b_moe  = (const float*)d_in[5];
    const float* Wg     = (const float*)d_in[6];
    const float* bg     = (const float*)d_in[7];
    const float* Wq_e   = (const float*)d_in[8];
    const float* Wk_e   = (const float*)d_in[9];
    const float* Wv_e   = (const float*)d_in[10];
    const float* Wo_e   = (const float*)d_in[11];
    const float* g_np   = (const float*)d_in[12];
    const float* b_np   = (const float*)d_in[13];
    const float* Wi_p   = (const float*)d_in[14];
    const float* bi_p   = (const float*)d_in[15];
    const float* Wo_p   = (const float*)d_in[16];
    const float* bo_p   = (const float*)d_in[17];
    const float* W_pe   = (const float*)d_in[18];
    const float* b_pe   = (const float*)d_in[19];
    const float* g_nh   = (const float*)d_in[20];
    const float* b_nh   = (const float*)d_in[21];
    const float* Wi_f   = (const float*)d_in[22];
    const float* bi_f   = (const float*)d_in[23];
    const float* Wo_f   = (const float*)d_in[24];
    const float* bo_f   = (const float*)d_in[25];
    const float* g_nfh  = (const float*)d_in[26];
    const float* b_nfh  = (const float*)d_in[27];
    const float* Wq_a   = (const float*)d_in[28];
    const float* bq_a   = (const float*)d_in[29];
    const float* Wk_a   = (const float*)d_in[30];
    const float* bk_a   = (const float*)d_in[31];
    const float* Wv_a   = (const float*)d_in[32];
    const float* bv_a   = (const float*)d_in[33];
    const float* Wd     = (const float*)d_in[34];
    const float* bd     = (const float*)d_in[35];
    const float* g_ln   = (const float*)d_in[36];
    const float* b_ln   = (const float*)d_in[37];
    float* out = (float*)d_out;
    char* ob = (char*)d_out;
    char* wb = (char*)d_ws;

    // bf16 slabs: ws = W0|W1 (16 MiB each); d_out doubles as O0|O1.
    u16* W0 = (u16*)(wb + 0LL * 16 * MB);
    u16* W1 = (u16*)(wb + 1LL * 16 * MB);
    u16* O0 = (u16*)(ob + 0LL * 16 * MB);
    u16* O1 = (u16*)(ob + 1LL * 16 * MB);

    // Stage A fp32 scratch: in d_out (lifetime-disjoint with O0/O1 use) and
    // in ws (o_qe under W0's slab, o_geo under W1's slab — both dead before
    // W0/W1 are first written in stages B/C).
    float* o_xs   = (float*)(ob + 0LL  * MB);
    float* o_ke   = (float*)(ob + 4LL  * MB);
    float* o_ve   = (float*)(ob + 7LL  * MB);
    float* o_pri  = (float*)(ob + 10LL * MB);
    float* o_np64 = (float*)(ob + 14LL * MB);
    float* o_qkv  = (float*)(ob + 18LL * MB);
    float* o_attp = (float*)(ob + 0LL  * MB);
    float* o_tmp  = (float*)(ob + 4LL  * MB);
    float* o_qe   = (float*)(wb + 0LL  * MB);   // [3,16384,64] = 12 MiB
    float* o_geo  = (float*)(wb + 16LL * MB);   // [16384,192]  = 12.6 MiB

    dim3 blk(256);
    const float* fnull = nullptr;

    // ---- A: MoE priori (decomposed: GEMM q_e -> batched attn+gate -> GEMM) ----
    gemm_mfma<float, float, float><<<dim3(1, 128), blk, 0, stream>>>(     // xs
        tag, 512, 0, W_moe, 64, 0, b_moe, fnull, 0, o_xs, 64, 0, 512, 64);
    gemm_mfma<float, float, float><<<dim3(1, 32, 3), blk, 0, stream>>>(   // k_e
        refs, 512, 4096LL * 512, Wk_e, 64, 512LL * 64, nullptr, fnull, 0,
        o_ke, 64, 4096LL * 64, 512, 64);
    gemm_mfma<float, float, float><<<dim3(1, 32, 3), blk, 0, stream>>>(   // v_e
        refs, 512, 4096LL * 512, Wv_e, 64, 512LL * 64, nullptr, fnull, 0,
        o_ve, 64, 4096LL * 64, 512, 64);
    gemm_mfma<float, float, float><<<dim3(1, 128, 3), blk, 0, stream>>>(  // q_e
        o_xs, 64, 0, Wq_e, 64, 4096LL, nullptr, fnull, 0,
        o_qe, 64, 16384LL * 64, 64, 64);
    moe_attn_k<<<dim3(3, 128), dim3(128), 0, stream>>>(                   // geo = gate*eo
        o_qe, o_ke, o_ve, o_xs, Wg, bg, o_geo);
    gemm_mfma<float, float, float><<<dim3(1, 128), blk, 0, stream>>>(     // priori = geo @ Wo_cat
        o_geo, 192, 0, Wo_e, 64, 0, nullptr, fnull, 0, o_pri, 64, 0, 192, 64);

    // ---- B: priori causal self-MHA + expansion to 512 ----
    ln64_k<<<dim3(4096), blk, 0, stream>>>(o_pri, g_np, b_np, o_np64, 16384);
    gemm_mfma<float, float, float><<<dim3(2, 128), blk, 0, stream>>>(     // qkv_p
        o_np64, 64, 0, Wi_p, 192, 0, bi_p, fnull, 0, o_qkv, 192, 0, 64, 192);
    attn_small_k<<<dim3(8, 128), dim3(128), 0, stream>>>(o_qkv, o_attp);
    gemm_mfma<float, float, float><<<dim3(1, 128), blk, 0, stream>>>(     // tmp64
        o_attp, 64, 0, Wo_p, 64, 0, bo_p, o_pri, 64, o_tmp, 64, 0, 64, 64);
    gemm_mfma<float, float, u16><<<dim3(4, 128), blk, 0, stream>>>(       // priori_e -> W0
        o_tmp, 64, 0, W_pe, 512, 0, b_pe, fnull, 0, W0, 512, 0, 64, 512);

    // ---- C: fusion cross-MHA ----
    ln512_t<u16, u16><<<dim3(16384), blk, 0, stream>>>(W0, g_nh, b_nh, W0, 1e-5f); // npri
    gemm_mfma<u16, float, u16><<<dim3(4, 128), blk, 0, stream>>>(                   // Kf -> O1
        W0, 512, 0, Wi_f + 512, 1536, 0, bi_f + 512, fnull, 0, O1, 512, 0, 512, 512);
    gemm_mfma<u16, float, u16><<<dim3(4, 128), blk, 0, stream>>>(                   // Vf -> W1
        W0, 512, 0, Wi_f + 1024, 1536, 0, bi_f + 1024, fnull, 0, W1, 512, 0, 512, 512);
    gemm_mfma<float, float, u16><<<dim3(4, 128), blk, 0, stream>>>(                 // Qf -> O0
        hidden, 512, 0, Wi_f, 1536, 0, bi_f, fnull, 0, O0, 512, 0, 512, 512);
    attn_bf_k<<<dim3(8, 128), dim3(128), 0, stream>>>(O0, O1, W1, W0, 128, 1);      // attn -> W0
    gemm_mfma<u16, float, u16><<<dim3(4, 128), blk, 0, stream>>>(                   // hidden2 -> O0
        W0, 512, 0, Wo_f, 512, 0, bo_f, hidden, 512, O0, 512, 0, 512, 512);

    // ---- D: feat cross-attention ----
    ln512_t<u16, u16><<<dim3(16384), blk, 0, stream>>>(O0, g_nfh, b_nfh, O0, 1e-5f); // nh
    gemm_mfma<u16, float, u16><<<dim3(4, 128), blk, 0, stream>>>(                    // q_a -> O1
        O0, 512, 0, Wq_a, 512, 0, bq_a, fnull, 0, O1, 512, 0, 512, 512);
    gemm_mfma<float, float, u16><<<dim3(4, 84), blk, 0, stream>>>(                   // k_a -> W0
        feats, 512, 0, Wk_a, 512, 0, bk_a, fnull, 0, W0, 512, 0, 512, 512);
    gemm_mfma<float, float, u16><<<dim3(4, 84), blk, 0, stream>>>(                   // v_a -> W1
        feats, 512, 0, Wv_a, 512, 0, bv_a, fnull, 0, W1, 512, 0, 512, 512);
    attn_bf_k<<<dim3(8, 128), dim3(128), 0, stream>>>(O1, W0, W1, O1, 84, 0);        // ctx in-place
    gemm_mfma<u16, u16, u16><<<dim3(4, 128), blk, 0, stream>>>(                      // ctxd -> W0
        O1, 512, 0, Wd, 512, 0, bd, O0, 512, W0, 512, 0, 512, 512);

    // ---- E: final post-LN (eps=1e-12) -> fp32 d_out ----
    ln512_t<u16, float><<<dim3(16384), blk, 0, stream>>>(W0, g_ln, b_ln, out, 1e-12f);
}

// Round 2
// 1108.745 us; speedup vs baseline: 1.1981x; 1.0179x over previous
//
#include <hip/hip_runtime.h>
#include <hip/hip_bf16.h>

typedef unsigned short u16;
typedef unsigned int   u32;
typedef __attribute__((ext_vector_type(8))) short short8;   // 8 bf16 (4 VGPRs)
typedef __attribute__((ext_vector_type(4))) float f32x4;

#define BBt 128
#define SS 128
#define RR 32
#define NEx 3
#define MB (1024 * 1024)

static __device__ __forceinline__ float bs2f(u16 u){ return __uint_as_float(((u32)u) << 16); }
static __device__ __forceinline__ float blo(u32 u){ return __uint_as_float(u << 16); }
static __device__ __forceinline__ float bhi(u32 u){ return __uint_as_float(u & 0xffff0000u); }
static __device__ __forceinline__ u16 f2bs(float x){
    u32 u = __float_as_uint(x);
    u += 0x7fff + ((u >> 16) & 1);          // RNE
    return (u16)(u >> 16);
}
static __device__ __forceinline__ float ldany(const float* p){ return *p; }
static __device__ __forceinline__ float ldany(const u16* p){ return bs2f(*p); }

// ===========================================================================
// MFMA GEMM: C[M,N] = A[M,K] @ W[K,N] (+bias) (+Res).
// BM=128, BN=128 (cols >= Ncols masked), BK=32, 256 threads (4 waves 2x2).
// A: fp32 or bf16. W: fp32 row-major (transposed to LDS). C: fp32 or bf16.
// M % 128 == 0 (grid covers), K % 32 == 0, Ncols % 8 == 0. Batched via z.
// ===========================================================================
template<typename TA, typename TRes, typename TC>
__global__ __launch_bounds__(256) void gemm_mfma(
    const TA* __restrict__ A, int lda, long long sA,
    const float* __restrict__ W, int ldw, long long sW,
    const float* __restrict__ bias,
    const TRes* __restrict__ Res, int ldr,
    TC* __restrict__ C, int ldc, long long sC,
    int K, int Ncols)
{
    int bz = blockIdx.z;
    A += (long long)bz * sA;
    W += (long long)bz * sW;
    C += (long long)bz * sC;

    __shared__ __align__(16) u16 As[128][40];   // [m][k]
    __shared__ __align__(16) u16 Bs[128][40];   // [n][k] (W transposed)

    int tid = threadIdx.x;
    long long row0 = (long long)blockIdx.y * 128;
    int col0 = blockIdx.x * 128;

    int wid = tid >> 6, lane = tid & 63;
    int wm = (wid >> 1) * 64, wn = (wid & 1) * 64;
    int l15 = lane & 15, quad = lane >> 4;

    f32x4 acc[4][4];
    #pragma unroll
    for (int i = 0; i < 4; ++i)
        #pragma unroll
        for (int j = 0; j < 4; ++j)
            acc[i][j] = (f32x4){0.f, 0.f, 0.f, 0.f};

    int ar = tid >> 1, ak = (tid & 1) * 16;
    int bk0 = (tid & 15) * 2, bn0 = (tid >> 4) * 8;

    for (int kt = 0; kt < K; kt += 32) {
        {   // ---- stage A tile [128,32] -> bf16 ----
            const TA* src = A + (row0 + ar) * lda + kt + ak;
            if constexpr (sizeof(TA) == 4) {
                u16 tmp[16];
                #pragma unroll
                for (int t = 0; t < 16; t += 4) {
                    float4 f = *(const float4*)(src + t);
                    tmp[t] = f2bs(f.x); tmp[t+1] = f2bs(f.y);
                    tmp[t+2] = f2bs(f.z); tmp[t+3] = f2bs(f.w);
                }
                *(uint4*)&As[ar][ak]     = *(const uint4*)&tmp[0];
                *(uint4*)&As[ar][ak + 8] = *(const uint4*)&tmp[8];
            } else {
                *(uint4*)&As[ar][ak]     = *(const uint4*)(src);
                *(uint4*)&As[ar][ak + 8] = *(const uint4*)(src + 8);
            }
        }
        {   // ---- stage W tile [32,128] transposed -> Bs[n][k], N-guarded ----
            if (col0 + bn0 < Ncols) {
                const float* w0 = W + (long long)(kt + bk0) * ldw + col0 + bn0;
                const float* w1 = w0 + ldw;
                float r0[8], r1[8];
                *(float4*)&r0[0] = *(const float4*)(w0);
                *(float4*)&r0[4] = *(const float4*)(w0 + 4);
                *(float4*)&r1[0] = *(const float4*)(w1);
                *(float4*)&r1[4] = *(const float4*)(w1 + 4);
                #pragma unroll
                for (int i = 0; i < 8; ++i) {
                    u32 packed = (u32)f2bs(r0[i]) | ((u32)f2bs(r1[i]) << 16);
                    *(u32*)&Bs[bn0 + i][bk0] = packed;
                }
            } else {
                #pragma unroll
                for (int i = 0; i < 8; ++i)
                    *(u32*)&Bs[bn0 + i][bk0] = 0u;
            }
        }
        __syncthreads();

        short8 af[4], bfr[4];
        #pragma unroll
        for (int mt = 0; mt < 4; ++mt)
            af[mt] = *(const short8*)&As[wm + mt * 16 + l15][quad * 8];
        #pragma unroll
        for (int nt = 0; nt < 4; ++nt)
            bfr[nt] = *(const short8*)&Bs[wn + nt * 16 + l15][quad * 8];
        #pragma unroll
        for (int mt = 0; mt < 4; ++mt)
            #pragma unroll
            for (int nt = 0; nt < 4; ++nt)
                acc[mt][nt] = __builtin_amdgcn_mfma_f32_16x16x32_bf16(
                    af[mt], bfr[nt], acc[mt][nt], 0, 0, 0);
        __syncthreads();
    }

    // ---- epilogue: C/D layout col=lane&15, row=quad*4+reg ----
    #pragma unroll
    for (int mt = 0; mt < 4; ++mt) {
        #pragma unroll
        for (int r = 0; r < 4; ++r) {
            long long row = row0 + wm + mt * 16 + quad * 4 + r;
            #pragma unroll
            for (int nt = 0; nt < 4; ++nt) {
                int col = col0 + wn + nt * 16 + l15;
                if (col >= Ncols) continue;
                float v = acc[mt][nt][r];
                if (bias) v += bias[col];
                if (Res)  v += ldany(&Res[row * ldr + col]);
                if constexpr (sizeof(TC) == 4) C[row * ldc + col] = v;
                else                           C[row * ldc + col] = f2bs(v);
            }
        }
    }
}

// ===========================================================================
// Flash attention v2, bf16 in/out. Block per (head,batch), thread per query.
// - flat float4 LDS staging (lane-consecutive -> conflict-free; the old
//   row-strided staging was a 64-way bank conflict, 1.8M/dispatch)
// - 4-accumulator QK dot (dependent chain 128 -> 16)
// - defer-max (THR=8): common PV path is pure fmaf, no corr multiply;
//   rescale only when __all(active lanes) sees s > m+8 (~first iter only)
// out may alias Q (all global reads precede the post-barrier stores).
// ===========================================================================
__global__ __launch_bounds__(128) void attn_bf_k(
    const u16* __restrict__ Q, const u16* __restrict__ K,
    const u16* __restrict__ V, u16* __restrict__ out,
    int L, int causal)
{
    int h = blockIdx.x, b = blockIdx.y;
    int tid = threadIdx.x;
    __shared__ __align__(16) u16 kS[128 * 64];
    __shared__ __align__(16) u16 vS[128 * 64];

    // flat staging: uint4 index i covers u16 [8i, 8i+8): r = i>>3, c8 = i&7
    for (int i = tid; i < L * 8; i += 128) {
        int r = i >> 3, c8 = i & 7;
        long long gsrc = ((long long)b * L + r) * 512 + h * 64 + c8 * 8;
        ((uint4*)kS)[i] = *(const uint4*)&K[gsrc];
        ((uint4*)vS)[i] = *(const uint4*)&V[gsrc];
    }
    float q[64];
    {
        const u32* qp = (const u32*)&Q[((long long)b * 128 + tid) * 512 + h * 64];
        #pragma unroll
        for (int t = 0; t < 32; ++t) {
            u32 u = qp[t];
            q[2*t]   = blo(u) * 0.125f;
            q[2*t+1] = bhi(u) * 0.125f;
        }
    }
    __syncthreads();

    int jmax = causal ? tid : (L - 1);
    float m = -1e30f, l = 0.f;
    float acc[64];
    #pragma unroll
    for (int d = 0; d < 64; ++d) acc[d] = 0.f;

    for (int j = 0; j <= jmax; ++j) {
        const uint4* kr = (const uint4*)&kS[j * 64];
        float a0 = 0.f, a1 = 0.f, a2 = 0.f, a3 = 0.f;
        #pragma unroll
        for (int t = 0; t < 8; ++t) {
            uint4 u4 = kr[t];
            u32 uu[4] = {u4.x, u4.y, u4.z, u4.w};
            #pragma unroll
            for (int e = 0; e < 4; ++e) {
                int d = t * 8 + e * 2;
                if (e & 1) {
                    a2 = fmaf(q[d],   blo(uu[e]), a2);
                    a3 = fmaf(q[d+1], bhi(uu[e]), a3);
                } else {
                    a0 = fmaf(q[d],   blo(uu[e]), a0);
                    a1 = fmaf(q[d+1], bhi(uu[e]), a1);
                }
            }
        }
        float s = (a0 + a1) + (a2 + a3);
        const uint4* vr = (const uint4*)&vS[j * 64];
        if (__all(s <= m + 8.f)) {
            // fast path: no rescale, pure fma accumulate
            float p = __expf(s - m);
            l += p;
            #pragma unroll
            for (int t = 0; t < 8; ++t) {
                uint4 u4 = vr[t];
                u32 uu[4] = {u4.x, u4.y, u4.z, u4.w};
                #pragma unroll
                for (int e = 0; e < 4; ++e) {
                    int d = t * 8 + e * 2;
                    acc[d]   = fmaf(p, blo(uu[e]), acc[d]);
                    acc[d+1] = fmaf(p, bhi(uu[e]), acc[d+1]);
                }
            }
        } else {
            // rescale path (rare: first iteration, or max jumped by >8)
            float mn = fmaxf(m, s);
            float corr = __expf(m - mn);
            float p = __expf(s - mn);
            l = l * corr + p;
            #pragma unroll
            for (int t = 0; t < 8; ++t) {
                uint4 u4 = vr[t];
                u32 uu[4] = {u4.x, u4.y, u4.z, u4.w};
                #pragma unroll
                for (int e = 0; e < 4; ++e) {
                    int d = t * 8 + e * 2;
                    acc[d]   = fmaf(p, blo(uu[e]), acc[d]   * corr);
                    acc[d+1] = fmaf(p, bhi(uu[e]), acc[d+1] * corr);
                }
            }
            m = mn;
        }
    }
    float inv = 1.f / l;
    u32 ou[32];
    #pragma unroll
    for (int t = 0; t < 32; ++t)
        ou[t] = (u32)f2bs(acc[2*t] * inv) | ((u32)f2bs(acc[2*t+1] * inv) << 16);
    uint4* op = (uint4*)&out[((long long)b * 128 + tid) * 512 + h * 64];
    #pragma unroll
    for (int t = 0; t < 8; ++t) op[t] = *(const uint4*)&ou[t * 4];
}

// ===========================================================================
// LayerNorm over 512, templated dtypes. In-place OK.
// ===========================================================================
template<typename TI, typename TO>
__global__ __launch_bounds__(256) void ln512_t(
    const TI* __restrict__ x, const float* __restrict__ g,
    const float* __restrict__ bt, TO* __restrict__ y, float eps)
{
    int row = blockIdx.x, tid = threadIdx.x;
    long long base = (long long)row * 512;
    float v0 = ldany(&x[base + tid]);
    float v1 = ldany(&x[base + 256 + tid]);
    float s = v0 + v1, ss = v0 * v0 + v1 * v1;
    #pragma unroll
    for (int o = 32; o >= 1; o >>= 1) { s += __shfl_xor(s, o); ss += __shfl_xor(ss, o); }
    __shared__ float red[2][4];
    int wave = tid >> 6, lane = tid & 63;
    if (lane == 0) { red[0][wave] = s; red[1][wave] = ss; }
    __syncthreads();
    s  = red[0][0] + red[0][1] + red[0][2] + red[0][3];
    ss = red[1][0] + red[1][1] + red[1][2] + red[1][3];
    float mean = s * (1.f / 512.f);
    float var = ss * (1.f / 512.f) - mean * mean;
    float rstd = rsqrtf(fmaxf(var, 0.f) + eps);
    float o0 = (v0 - mean) * rstd * g[tid]       + bt[tid];
    float o1 = (v1 - mean) * rstd * g[256 + tid] + bt[256 + tid];
    if constexpr (sizeof(TO) == 4) { y[base + tid] = o0; y[base + 256 + tid] = o1; }
    else { y[base + tid] = f2bs(o0); y[base + 256 + tid] = f2bs(o1); }
}

// ===========================================================================
// MoE expert attention v4: block = (expert e, batch b), thread = query s.
// Reads pre-projected q_e [3,16384,64]; K/V fp32 staged to LDS (broadcast
// reads, conflict-free). Two-pass softmax over R=32 entirely in registers.
// Fuses the gate: writes geo[row, e*64+d] = gate_e(row) * eo_e[row,d], so the
// gated combine collapses into ONE gemm: priori = geo[16384,192] @ Wo_cat,
// where Wo_cat is Wo_e [3,64,64] flattened row-major (= [192,64]).
// ===========================================================================
__global__ __launch_bounds__(128) void moe_attn_k(
    const float* __restrict__ qe,   // [3, B*S, 64]
    const float* __restrict__ ke,   // [3, B*R, 64]
    const float* __restrict__ ve,   // [3, B*R, 64]
    const float* __restrict__ xs,   // [B*S, 64] (for the gate)
    const float* __restrict__ Wg,   // [64,3]
    const float* __restrict__ bg,   // [3]
    float* __restrict__ geo)        // [B*S, 192]
{
    int e = blockIdx.x, b = blockIdx.y;
    int tid = threadIdx.x;
    __shared__ __align__(16) float kS[RR][64];
    __shared__ __align__(16) float vS[RR][64];

    {   // stage K/V tile for (e,b): 2048 floats each = 512 float4, coalesced
        const float4* ks = (const float4*)&ke[((long long)e * (BBt * RR) + (long long)b * RR) * 64];
        const float4* vs = (const float4*)&ve[((long long)e * (BBt * RR) + (long long)b * RR) * 64];
        float4* kd = (float4*)&kS[0][0];
        float4* vd = (float4*)&vS[0][0];
        #pragma unroll
        for (int t = 0; t < 4; ++t) {
            kd[tid + 128 * t] = ks[tid + 128 * t];
            vd[tid + 128 * t] = vs[tid + 128 * t];
        }
    }

    long long row = (long long)b * SS + tid;
    float q[64];
    {
        const float4* qp = (const float4*)&qe[((long long)e * (BBt * SS) + row) * 64];
        #pragma unroll
        for (int t = 0; t < 16; ++t) {
            float4 f = qp[t];
            q[4*t] = f.x; q[4*t+1] = f.y; q[4*t+2] = f.z; q[4*t+3] = f.w;
        }
    }

    // gate = softmax(xs_row @ Wg + bg)[e]
    float l0 = bg[0], l1 = bg[1], l2 = bg[2];
    {
        const float4* xr = (const float4*)&xs[row * 64];
        #pragma unroll
        for (int t = 0; t < 16; ++t) {
            float4 f = xr[t];
            float xv[4] = {f.x, f.y, f.z, f.w};
            #pragma unroll
            for (int u = 0; u < 4; ++u) {
                int j = 4 * t + u;
                l0 = fmaf(xv[u], Wg[j * 3 + 0], l0);
                l1 = fmaf(xv[u], Wg[j * 3 + 1], l1);
                l2 = fmaf(xv[u], Wg[j * 3 + 2], l2);
            }
        }
    }
    float mg = fmaxf(l0, fmaxf(l1, l2));
    float g0 = __expf(l0 - mg), g1 = __expf(l1 - mg), g2 = __expf(l2 - mg);
    float gate = (e == 0 ? g0 : (e == 1 ? g1 : g2)) / (g0 + g1 + g2);

    __syncthreads();

    // scores (two-pass softmax, all in registers)
    float s[RR];
    #pragma unroll
    for (int r = 0; r < RR; ++r) {
        float a0 = 0.f, a1 = 0.f, a2 = 0.f, a3 = 0.f;
        const float4* kr = (const float4*)&kS[r][0];
        #pragma unroll
        for (int t = 0; t < 16; ++t) {
            float4 f = kr[t];
            a0 = fmaf(q[4*t],   f.x, a0);
            a1 = fmaf(q[4*t+1], f.y, a1);
            a2 = fmaf(q[4*t+2], f.z, a2);
            a3 = fmaf(q[4*t+3], f.w, a3);
        }
        s[r] = ((a0 + a1) + (a2 + a3)) * 0.125f;   // 1/sqrt(64)
    }
    float m = s[0];
    #pragma unroll
    for (int r = 1; r < RR; ++r) m = fmaxf(m, s[r]);
    float l = 0.f;
    #pragma unroll
    for (int r = 0; r < RR; ++r) { s[r] = __expf(s[r] - m); l += s[r]; }
    float scale = gate / l;

    // PV
    float acc[64];
    #pragma unroll
    for (int d = 0; d < 64; ++d) acc[d] = 0.f;
    #pragma unroll
    for (int r = 0; r < RR; ++r) {
        float p = s[r];
        const float4* vr = (const float4*)&vS[r][0];
        #pragma unroll
        for (int t = 0; t < 16; ++t) {
            float4 f = vr[t];
            acc[4*t]   = fmaf(p, f.x, acc[4*t]);
            acc[4*t+1] = fmaf(p, f.y, acc[4*t+1]);
            acc[4*t+2] = fmaf(p, f.z, acc[4*t+2]);
            acc[4*t+3] = fmaf(p, f.w, acc[4*t+3]);
        }
    }
    float4* op = (float4*)&geo[row * 192 + e * 64];
    #pragma unroll
    for (int t = 0; t < 16; ++t) {
        float4 f;
        f.x = acc[4*t] * scale;   f.y = acc[4*t+1] * scale;
        f.z = acc[4*t+2] * scale; f.w = acc[4*t+3] * scale;
        op[t] = f;
    }
}

// ===========================================================================
// Small causal MHA on 64-dim priori (H=8, dh=8, S=128). qkv packed [B*S,192].
// ===========================================================================
__global__ __launch_bounds__(128) void attn_small_k(
    const float* __restrict__ qkv, float* __restrict__ out)
{
    int h = blockIdx.x, b = blockIdx.y;
    int tid = threadIdx.x;
    __shared__ float kS[SS][9], vS[SS][9];
    long long base = ((long long)b * SS + tid) * 192;
    #pragma unroll
    for (int d = 0; d < 8; ++d) {
        kS[tid][d] = qkv[base + 64 + h * 8 + d];
        vS[tid][d] = qkv[base + 128 + h * 8 + d];
    }
    float q[8];
    #pragma unroll
    for (int d = 0; d < 8; ++d)
        q[d] = qkv[base + h * 8 + d] * 0.35355339059327373f;
    __syncthreads();

    float m = -1e30f, l = 0.f, acc[8] = {};
    for (int j = 0; j <= tid; ++j) {
        float s = 0.f;
        #pragma unroll
        for (int d = 0; d < 8; ++d) s = fmaf(q[d], kS[j][d], s);
        float mn = fmaxf(m, s);
        float corr = __expf(m - mn);
        float p = __expf(s - mn);
        l = l * corr + p;
        #pragma unroll
        for (int d = 0; d < 8; ++d) acc[d] = fmaf(p, vS[j][d], acc[d] * corr);
        m = mn;
    }
    float inv = 1.f / l;
    #pragma unroll
    for (int d = 0; d < 8; ++d)
        out[((long long)b * SS + tid) * 64 + h * 8 + d] = acc[d] * inv;
}

__global__ __launch_bounds__(256) void ln64_k(
    const float* __restrict__ x, const float* __restrict__ g,
    const float* __restrict__ bt, float* __restrict__ y, int M)
{
    int wave = threadIdx.x >> 6, lane = threadIdx.x & 63;
    int row = blockIdx.x * 4 + wave;
    if (row >= M) return;
    long long base = (long long)row * 64;
    float v = x[base + lane];
    float s = v, ss = v * v;
    #pragma unroll
    for (int o = 32; o >= 1; o >>= 1) { s += __shfl_xor(s, o); ss += __shfl_xor(ss, o); }
    float mean = s * (1.f / 64.f);
    float var = ss * (1.f / 64.f) - mean * mean;
    float rstd = rsqrtf(fmaxf(var, 0.f) + 1e-5f);
    y[base + lane] = (v - mean) * rstd * g[lane] + bt[lane];
}

// ===========================================================================
extern "C" void kernel_launch(void* const* d_in, const int* in_sizes, int n_in,
                              void* d_out, int out_size, void* d_ws, size_t ws_size,
                              hipStream_t stream)
{
    (void)in_sizes; (void)n_in; (void)out_size; (void)ws_size;
    const float* hidden = (const float*)d_in[0];
    const float* tag    = (const float*)d_in[1];
    const float* feats  = (const float*)d_in[2];
    const float* refs   = (const float*)d_in[3];
    const float* W_moe  = (const float*)d_in[4];
    const float* b_moe  = (const float*)d_in[5];
    const float* Wg     = (const float*)d_in[6];
    const float* bg     = (const float*)d_in[7];
    const float* Wq_e   = (const float*)d_in[8];
    const float* Wk_e   = (const float*)d_in[9];
    const float* Wv_e   = (const float*)d_in[10];
    const float* Wo_e   = (const float*)d_in[11];
    const float* g_np   = (const float*)d_in[12];
    const float* b_np   = (const float*)d_in[13];
    const float* Wi_p   = (const float*)d_in[14];
    const float* bi_p   = (const float*)d_in[15];
    const float* Wo_p   = (const float*)d_in[16];
    const float* bo_p   = (const float*)d_in[17];
    const float* W_pe   = (const float*)d_in[18];
    const float* b_pe   = (const float*)d_in[19];
    const float* g_nh   = (const float*)d_in[20];
    const float* b_nh   = (const float*)d_in[21];
    const float* Wi_f   = (const float*)d_in[22];
    const float* bi_f   = (const float*)d_in[23];
    const float* Wo_f   = (const float*)d_in[24];
    const float* bo_f   = (const float*)d_in[25];
    const float* g_nfh  = (const float*)d_in[26];
    const float* b_nfh  = (const float*)d_in[27];
    const float* Wq_a   = (const float*)d_in[28];
    const float* bq_a   = (const float*)d_in[29];
    const float* Wk_a   = (const float*)d_in[30];
    const float* bk_a   = (const float*)d_in[31];
    const float* Wv_a   = (const float*)d_in[32];
    const float* bv_a   = (const float*)d_in[33];
    const float* Wd     = (const float*)d_in[34];
    const float* bd     = (const float*)d_in[35];
    const float* g_ln   = (const float*)d_in[36];
    const float* b_ln   = (const float*)d_in[37];
    float* out = (float*)d_out;
    char* ob = (char*)d_out;
    char* wb = (char*)d_ws;

    // bf16 slabs: ws = W0|W1 (16 MiB each); d_out doubles as O0|O1.
    u16* W0 = (u16*)(wb + 0LL * 16 * MB);
    u16* W1 = (u16*)(wb + 1LL * 16 * MB);
    u16* O0 = (u16*)(ob + 0LL * 16 * MB);
    u16* O1 = (u16*)(ob + 1LL * 16 * MB);

    // Stage A fp32 scratch: in d_out (lifetime-disjoint with O0/O1 use) and
    // in ws (o_qe under W0's slab, o_geo under W1's slab — both dead before
    // W0/W1 are first written in stages B/C).
    float* o_xs   = (float*)(ob + 0LL  * MB);
    float* o_ke   = (float*)(ob + 4LL  * MB);
    float* o_ve   = (float*)(ob + 7LL  * MB);
    float* o_pri  = (float*)(ob + 10LL * MB);
    float* o_np64 = (float*)(ob + 14LL * MB);
    float* o_qkv  = (float*)(ob + 18LL * MB);
    float* o_attp = (float*)(ob + 0LL  * MB);
    float* o_tmp  = (float*)(ob + 4LL  * MB);
    float* o_qe   = (float*)(wb + 0LL  * MB);   // [3,16384,64] = 12 MiB
    float* o_geo  = (float*)(wb + 16LL * MB);   // [16384,192]  = 12.6 MiB

    dim3 blk(256);
    const float* fnull = nullptr;

    // ---- A: MoE priori (decomposed: GEMM q_e -> batched attn+gate -> GEMM) ----
    gemm_mfma<float, float, float><<<dim3(1, 128), blk, 0, stream>>>(     // xs
        tag, 512, 0, W_moe, 64, 0, b_moe, fnull, 0, o_xs, 64, 0, 512, 64);
    gemm_mfma<float, float, float><<<dim3(1, 32, 3), blk, 0, stream>>>(   // k_e
        refs, 512, 4096LL * 512, Wk_e, 64, 512LL * 64, nullptr, fnull, 0,
        o_ke, 64, 4096LL * 64, 512, 64);
    gemm_mfma<float, float, float><<<dim3(1, 32, 3), blk, 0, stream>>>(   // v_e
        refs, 512, 4096LL * 512, Wv_e, 64, 512LL * 64, nullptr, fnull, 0,
        o_ve, 64, 4096LL * 64, 512, 64);
    gemm_mfma<float, float, float><<<dim3(1, 128, 3), blk, 0, stream>>>(  // q_e
        o_xs, 64, 0, Wq_e, 64, 4096LL, nullptr, fnull, 0,
        o_qe, 64, 16384LL * 64, 64, 64);
    moe_attn_k<<<dim3(3, 128), dim3(128), 0, stream>>>(                   // geo = gate*eo
        o_qe, o_ke, o_ve, o_xs, Wg, bg, o_geo);
    gemm_mfma<float, float, float><<<dim3(1, 128), blk, 0, stream>>>(     // priori = geo @ Wo_cat
        o_geo, 192, 0, Wo_e, 64, 0, nullptr, fnull, 0, o_pri, 64, 0, 192, 64);

    // ---- B: priori causal self-MHA + expansion to 512 ----
    ln64_k<<<dim3(4096), blk, 0, stream>>>(o_pri, g_np, b_np, o_np64, 16384);
    gemm_mfma<float, float, float><<<dim3(2, 128), blk, 0, stream>>>(     // qkv_p
        o_np64, 64, 0, Wi_p, 192, 0, bi_p, fnull, 0, o_qkv, 192, 0, 64, 192);
    attn_small_k<<<dim3(8, 128), dim3(128), 0, stream>>>(o_qkv, o_attp);
    gemm_mfma<float, float, float><<<dim3(1, 128), blk, 0, stream>>>(     // tmp64
        o_attp, 64, 0, Wo_p, 64, 0, bo_p, o_pri, 64, o_tmp, 64, 0, 64, 64);
    gemm_mfma<float, float, u16><<<dim3(4, 128), blk, 0, stream>>>(       // priori_e -> W0
        o_tmp, 64, 0, W_pe, 512, 0, b_pe, fnull, 0, W0, 512, 0, 64, 512);

    // ---- C: fusion cross-MHA ----
    ln512_t<u16, u16><<<dim3(16384), blk, 0, stream>>>(W0, g_nh, b_nh, W0, 1e-5f); // npri
    gemm_mfma<u16, float, u16><<<dim3(4, 128), blk, 0, stream>>>(                   // Kf -> O1
        W0, 512, 0, Wi_f + 512, 1536, 0, bi_f + 512, fnull, 0, O1, 512, 0, 512, 512);
    gemm_mfma<u16, float, u16><<<dim3(4, 128), blk, 0, stream>>>(                   // Vf -> W1
        W0, 512, 0, Wi_f + 1024, 1536, 0, bi_f + 1024, fnull, 0, W1, 512, 0, 512, 512);
    gemm_mfma<float, float, u16><<<dim3(4, 128), blk, 0, stream>>>(                 // Qf -> O0
        hidden, 512, 0, Wi_f, 1536, 0, bi_f, fnull, 0, O0, 512, 0, 512, 512);
    attn_bf_k<<<dim3(8, 128), dim3(128), 0, stream>>>(O0, O1, W1, W0, 128, 1);      // attn -> W0
    gemm_mfma<u16, float, u16><<<dim3(4, 128), blk, 0, stream>>>(                   // hidden2 -> O0
        W0, 512, 0, Wo_f, 512, 0, bo_f, hidden, 512, O0, 512, 0, 512, 512);

    // ---- D: feat cross-attention ----
    ln512_t<u16, u16><<<dim3(16384), blk, 0, stream>>>(O0, g_nfh, b_nfh, O0, 1e-5f); // nh
    gemm_mfma<u16, float, u16><<<dim3(4, 128), blk, 0, stream>>>(                    // q_a -> O1
        O0, 512, 0, Wq_a, 512, 0, bq_a, fnull, 0, O1, 512, 0, 512, 512);
    gemm_mfma<float, float, u16><<<dim3(4, 84), blk, 0, stream>>>(                   // k_a -> W0
        feats, 512, 0, Wk_a, 512, 0, bk_a, fnull, 0, W0, 512, 0, 512, 512);
    gemm_mfma<float, float, u16><<<dim3(4, 84), blk, 0, stream>>>(                   // v_a -> W1
        feats, 512, 0, Wv_a, 512, 0, bv_a, fnull, 0, W1, 512, 0, 512, 512);
    attn_bf_k<<<dim3(8, 128), dim3(128), 0, stream>>>(O1, W0, W1, O1, 84, 0);        // ctx in-place
    gemm_mfma<u16, u16, u16><<<dim3(4, 128), blk, 0, stream>>>(                      // ctxd -> W0
        O1, 512, 0, Wd, 512, 0, bd, O0, 512, W0, 512, 0, 512, 512);

    // ---- E: final post-LN (eps=1e-12) -> fp32 d_out ----
    ln512_t<u16, float><<<dim3(16384), blk, 0, stream>>>(W0, g_ln, b_ln, out, 1e-12f);
}

// Round 3
// 936.717 us; speedup vs baseline: 1.4181x; 1.1836x over previous
//
#include <hip/hip_runtime.h>
#include <hip/hip_bf16.h>

typedef unsigned short u16;
typedef unsigned int   u32;
typedef __attribute__((ext_vector_type(8))) short short8;   // 8 bf16 (4 VGPRs)
typedef __attribute__((ext_vector_type(4))) float f32x4;

#define BBt 128
#define SS 128
#define RR 32
#define NEx 3
#define MB (1024 * 1024)

static __device__ __forceinline__ float bs2f(u16 u){ return __uint_as_float(((u32)u) << 16); }
static __device__ __forceinline__ float blo(u32 u){ return __uint_as_float(u << 16); }
static __device__ __forceinline__ float bhi(u32 u){ return __uint_as_float(u & 0xffff0000u); }
static __device__ __forceinline__ u16 f2bs(float x){
    u32 u = __float_as_uint(x);
    u += 0x7fff + ((u >> 16) & 1);          // RNE
    return (u16)(u >> 16);
}
static __device__ __forceinline__ float ldany(const float* p){ return *p; }
static __device__ __forceinline__ float ldany(const u16* p){ return bs2f(*p); }

// ===========================================================================
// MFMA GEMM: C[M,N] = A[M,K] @ W[K,N] (+bias) (+Res).
// BM=128, BN=128 (cols >= Ncols masked), BK=32, 256 threads (4 waves 2x2).
// A: fp32 or bf16. W: fp32 row-major (transposed to LDS). C: fp32 or bf16.
// M % 128 == 0 (grid covers), K % 32 == 0, Ncols % 8 == 0. Batched via z.
// ===========================================================================
template<typename TA, typename TRes, typename TC>
__global__ __launch_bounds__(256) void gemm_mfma(
    const TA* __restrict__ A, int lda, long long sA,
    const float* __restrict__ W, int ldw, long long sW,
    const float* __restrict__ bias,
    const TRes* __restrict__ Res, int ldr,
    TC* __restrict__ C, int ldc, long long sC,
    int K, int Ncols)
{
    int bz = blockIdx.z;
    A += (long long)bz * sA;
    W += (long long)bz * sW;
    C += (long long)bz * sC;

    __shared__ __align__(16) u16 As[128][40];   // [m][k]
    __shared__ __align__(16) u16 Bs[128][40];   // [n][k] (W transposed)

    int tid = threadIdx.x;
    long long row0 = (long long)blockIdx.y * 128;
    int col0 = blockIdx.x * 128;

    int wid = tid >> 6, lane = tid & 63;
    int wm = (wid >> 1) * 64, wn = (wid & 1) * 64;
    int l15 = lane & 15, quad = lane >> 4;

    f32x4 acc[4][4];
    #pragma unroll
    for (int i = 0; i < 4; ++i)
        #pragma unroll
        for (int j = 0; j < 4; ++j)
            acc[i][j] = (f32x4){0.f, 0.f, 0.f, 0.f};

    int ar = tid >> 1, ak = (tid & 1) * 16;
    int bk0 = (tid & 15) * 2, bn0 = (tid >> 4) * 8;

    for (int kt = 0; kt < K; kt += 32) {
        {   // ---- stage A tile [128,32] -> bf16 ----
            const TA* src = A + (row0 + ar) * lda + kt + ak;
            if constexpr (sizeof(TA) == 4) {
                u16 tmp[16];
                #pragma unroll
                for (int t = 0; t < 16; t += 4) {
                    float4 f = *(const float4*)(src + t);
                    tmp[t] = f2bs(f.x); tmp[t+1] = f2bs(f.y);
                    tmp[t+2] = f2bs(f.z); tmp[t+3] = f2bs(f.w);
                }
                *(uint4*)&As[ar][ak]     = *(const uint4*)&tmp[0];
                *(uint4*)&As[ar][ak + 8] = *(const uint4*)&tmp[8];
            } else {
                *(uint4*)&As[ar][ak]     = *(const uint4*)(src);
                *(uint4*)&As[ar][ak + 8] = *(const uint4*)(src + 8);
            }
        }
        {   // ---- stage W tile [32,128] transposed -> Bs[n][k], N-guarded ----
            if (col0 + bn0 < Ncols) {
                const float* w0 = W + (long long)(kt + bk0) * ldw + col0 + bn0;
                const float* w1 = w0 + ldw;
                float r0[8], r1[8];
                *(float4*)&r0[0] = *(const float4*)(w0);
                *(float4*)&r0[4] = *(const float4*)(w0 + 4);
                *(float4*)&r1[0] = *(const float4*)(w1);
                *(float4*)&r1[4] = *(const float4*)(w1 + 4);
                #pragma unroll
                for (int i = 0; i < 8; ++i) {
                    u32 packed = (u32)f2bs(r0[i]) | ((u32)f2bs(r1[i]) << 16);
                    *(u32*)&Bs[bn0 + i][bk0] = packed;
                }
            } else {
                #pragma unroll
                for (int i = 0; i < 8; ++i)
                    *(u32*)&Bs[bn0 + i][bk0] = 0u;
            }
        }
        __syncthreads();

        short8 af[4], bfr[4];
        #pragma unroll
        for (int mt = 0; mt < 4; ++mt)
            af[mt] = *(const short8*)&As[wm + mt * 16 + l15][quad * 8];
        #pragma unroll
        for (int nt = 0; nt < 4; ++nt)
            bfr[nt] = *(const short8*)&Bs[wn + nt * 16 + l15][quad * 8];
        #pragma unroll
        for (int mt = 0; mt < 4; ++mt)
            #pragma unroll
            for (int nt = 0; nt < 4; ++nt)
                acc[mt][nt] = __builtin_amdgcn_mfma_f32_16x16x32_bf16(
                    af[mt], bfr[nt], acc[mt][nt], 0, 0, 0);
        __syncthreads();
    }

    // ---- epilogue: C/D layout col=lane&15, row=quad*4+reg ----
    #pragma unroll
    for (int mt = 0; mt < 4; ++mt) {
        #pragma unroll
        for (int r = 0; r < 4; ++r) {
            long long row = row0 + wm + mt * 16 + quad * 4 + r;
            #pragma unroll
            for (int nt = 0; nt < 4; ++nt) {
                int col = col0 + wn + nt * 16 + l15;
                if (col >= Ncols) continue;
                float v = acc[mt][nt][r];
                if (bias) v += bias[col];
                if (Res)  v += ldany(&Res[row * ldr + col]);
                if constexpr (sizeof(TC) == 4) C[row * ldc + col] = v;
                else                           C[row * ldc + col] = f2bs(v);
            }
        }
    }
}

// ===========================================================================
// MFMA flash-less attention, bf16 in/out. Block per (head h, batch b).
// 4 waves x 32 query rows. Q[128,64], K[L,64], V[L,64] per (b,h), L <= 128.
// Fragment conventions identical to gemm_mfma (validated):
//   A-frag  lane(l15,quad) = A[l15][quad*8+i]
//   B-frag  lane(l15,quad) = B[quad*8+i][l15]
//   C/D     col = l15, row = quad*4 + reg
// S = Q @ K^T : B[k=d][n=kv] = K[kv][d]  -> kS natural [kv][d]
// O = P @ V   : B[k=kv][n=d] = V[kv][d]  -> vT transposed [d][kv]
// P round-trips through per-wave LDS (aliased over dead kS; one barrier).
// Causal waves skip tiles: nt <= 2w+1, ks <= w.
// out may alias Q (Q fully register-resident before any store).
// ===========================================================================
__global__ __launch_bounds__(256) void attn_mfma_k(
    const u16* __restrict__ Q, const u16* __restrict__ K,
    const u16* __restrict__ V, u16* __restrict__ out,
    int L, int causal)
{
    int h = blockIdx.x, b = blockIdx.y;
    int tid = threadIdx.x;
    int w = tid >> 6, lane = tid & 63;
    int l15 = lane & 15, quad = lane >> 4;

    int NTP = (L + 15) >> 4;          // padded kv tiles (6 or 8)
    int Lp  = NTP * 16;               // 96 or 128
    int ntmax = causal ? (2 * w + 1) : (NTP - 1);        // wave-uniform
    int ksmax = causal ? w : (((L + 31) >> 5) - 1);      // wave-uniform

    __shared__ __align__(16) u16 vT[64][136];            // V^T [d][kv], 17408 B
    __shared__ __align__(16) u16 pool[4][32][136];       // pS (aliases kS), 34816 B
    u16 (*kS)[72] = (u16(*)[72])&pool[0][0][0];          // [128][72] = 18432 B

    // ---- stage K natural [kv][d] (zero-pad rows >= L) ----
    for (int i = tid; i < Lp * 8; i += 256) {
        int r = i >> 3, c8 = i & 7;
        uint4 val = {0u, 0u, 0u, 0u};
        if (r < L) val = *(const uint4*)&K[((long long)b * L + r) * 512 + h * 64 + c8 * 8];
        *(uint4*)&kS[r][c8 * 8] = val;
    }
    // ---- stage V transposed [d][kv] (zero-pad kv >= L); kp = lane -> 2-way banks ----
    for (int i = tid; i < 512; i += 256) {       // dg = i>>6 in 0..7, kp = i&63
        int kp = i & 63, dg = i >> 6;
        int kv0 = kp * 2;
        if (kv0 < Lp) {
            uint4 r0 = {0u,0u,0u,0u}, r1 = {0u,0u,0u,0u};
            if (kv0 < L)     r0 = *(const uint4*)&V[((long long)b * L + kv0    ) * 512 + h * 64 + dg * 8];
            if (kv0 + 1 < L) r1 = *(const uint4*)&V[((long long)b * L + kv0 + 1) * 512 + h * 64 + dg * 8];
            u32 w0[4] = {r0.x, r0.y, r0.z, r0.w};
            u32 w1[4] = {r1.x, r1.y, r1.z, r1.w};
            #pragma unroll
            for (int j = 0; j < 4; ++j) {
                *(u32*)&vT[dg * 8 + 2 * j    ][kv0] = (w0[j] & 0xffffu) | (w1[j] << 16);
                *(u32*)&vT[dg * 8 + 2 * j + 1][kv0] = (w0[j] >> 16) | (w1[j] & 0xffff0000u);
            }
        }
    }

    // ---- Q fragments direct from global (A-frag layout) ----
    short8 qf[2][2];
    #pragma unroll
    for (int mt = 0; mt < 2; ++mt)
        #pragma unroll
        for (int ks = 0; ks < 2; ++ks)
            qf[mt][ks] = *(const short8*)&Q[((long long)b * 128 + w * 32 + mt * 16 + l15) * 512
                                            + h * 64 + ks * 32 + quad * 8];
    __syncthreads();

    // ---- S = Q @ K^T (tiles guarded by wave-uniform ntmax) ----
    f32x4 sacc[2][8];
    #pragma unroll
    for (int mt = 0; mt < 2; ++mt)
        #pragma unroll
        for (int nt = 0; nt < 8; ++nt)
            sacc[mt][nt] = (f32x4){0.f, 0.f, 0.f, 0.f};
    #pragma unroll
    for (int nt = 0; nt < 8; ++nt) {
        if (nt <= ntmax) {
            short8 kf0 = *(const short8*)&kS[nt * 16 + l15][quad * 8];
            short8 kf1 = *(const short8*)&kS[nt * 16 + l15][32 + quad * 8];
            #pragma unroll
            for (int mt = 0; mt < 2; ++mt) {
                sacc[mt][nt] = __builtin_amdgcn_mfma_f32_16x16x32_bf16(qf[mt][0], kf0, sacc[mt][nt], 0, 0, 0);
                sacc[mt][nt] = __builtin_amdgcn_mfma_f32_16x16x32_bf16(qf[mt][1], kf1, sacc[mt][nt], 0, 0, 0);
            }
        }
    }

    // ---- softmax over rows (cols = l15 lanes x nt tiles); scale 1/8 folded ----
    float pm[2][4], ls[2][4];
    #pragma unroll
    for (int mt = 0; mt < 2; ++mt) {
        #pragma unroll
        for (int r = 0; r < 4; ++r) pm[mt][r] = -1e30f;
        #pragma unroll
        for (int nt = 0; nt < 8; ++nt) {
            if (nt <= ntmax) {
                int col = nt * 16 + l15;
                #pragma unroll
                for (int r = 0; r < 4; ++r) {
                    int rowq = w * 32 + mt * 16 + quad * 4 + r;
                    bool bad = (col >= L) || (causal && col > rowq);
                    float sv = bad ? -1e30f : sacc[mt][nt][r];
                    sacc[mt][nt][r] = sv;
                    pm[mt][r] = fmaxf(pm[mt][r], sv);
                }
            }
        }
        #pragma unroll
        for (int r = 0; r < 4; ++r) {
            float mx = pm[mt][r];
            #pragma unroll
            for (int o = 1; o <= 8; o <<= 1) mx = fmaxf(mx, __shfl_xor(mx, o));
            pm[mt][r] = mx * 0.125f;           // scaled max
            ls[mt][r] = 0.f;
        }
        #pragma unroll
        for (int nt = 0; nt < 8; ++nt) {
            if (nt <= ntmax) {
                #pragma unroll
                for (int r = 0; r < 4; ++r) {
                    float p = __expf(fmaf(sacc[mt][nt][r], 0.125f, -pm[mt][r]));
                    sacc[mt][nt][r] = p;
                    ls[mt][r] += p;
                }
            }
        }
        #pragma unroll
        for (int r = 0; r < 4; ++r) {
            float sm = ls[mt][r];
            #pragma unroll
            for (int o = 1; o <= 8; o <<= 1) sm += __shfl_xor(sm, o);
            ls[mt][r] = 1.f / sm;
        }
    }

    __syncthreads();   // kS dead -> reuse as per-wave P tiles

    // ---- P -> bf16 -> per-wave LDS (pack col pairs via shfl, even l15 writes) ----
    u16 (*pW)[136] = (u16(*)[136])&pool[w][0][0];
    bool wl = (l15 & 1) == 0;
    #pragma unroll
    for (int mt = 0; mt < 2; ++mt)
        #pragma unroll
        for (int nt = 0; nt < 8; ++nt) {
            if (nt <= ntmax) {
                #pragma unroll
                for (int r = 0; r < 4; ++r) {
                    float pv = sacc[mt][nt][r];
                    float po = __shfl_xor(pv, 1);
                    if (wl) {
                        u32 packed = (u32)f2bs(pv) | ((u32)f2bs(po) << 16);
                        *(u32*)&pW[mt * 16 + quad * 4 + r][nt * 16 + l15] = packed;
                    }
                }
            }
        }

    // ---- O = P @ V (A-frag from pW, B-frag from vT) ----
    f32x4 oacc[2][4];
    #pragma unroll
    for (int mt = 0; mt < 2; ++mt)
        #pragma unroll
        for (int nd = 0; nd < 4; ++nd)
            oacc[mt][nd] = (f32x4){0.f, 0.f, 0.f, 0.f};
    #pragma unroll
    for (int ks = 0; ks < 4; ++ks) {
        if (ks <= ksmax) {
            short8 pf0 = *(const short8*)&pW[l15     ][ks * 32 + quad * 8];
            short8 pf1 = *(const short8*)&pW[16 + l15][ks * 32 + quad * 8];
            #pragma unroll
            for (int nd = 0; nd < 4; ++nd) {
                short8 vf = *(const short8*)&vT[nd * 16 + l15][ks * 32 + quad * 8];
                oacc[0][nd] = __builtin_amdgcn_mfma_f32_16x16x32_bf16(pf0, vf, oacc[0][nd], 0, 0, 0);
                oacc[1][nd] = __builtin_amdgcn_mfma_f32_16x16x32_bf16(pf1, vf, oacc[1][nd], 0, 0, 0);
            }
        }
    }

    // ---- write out (pack col pairs via shfl, even l15 writes u32) ----
    #pragma unroll
    for (int mt = 0; mt < 2; ++mt)
        #pragma unroll
        for (int nd = 0; nd < 4; ++nd)
            #pragma unroll
            for (int r = 0; r < 4; ++r) {
                float ov = oacc[mt][nd][r] * ls[mt][r];
                float oo = __shfl_xor(ov, 1);
                if (wl) {
                    long long rowq = (long long)b * 128 + w * 32 + mt * 16 + quad * 4 + r;
                    u32 packed = (u32)f2bs(ov) | ((u32)f2bs(oo) << 16);
                    *(u32*)&out[rowq * 512 + h * 64 + nd * 16 + l15] = packed;
                }
            }
}

// ===========================================================================
// LayerNorm over 512, templated dtypes. In-place OK.
// ===========================================================================
template<typename TI, typename TO>
__global__ __launch_bounds__(256) void ln512_t(
    const TI* __restrict__ x, const float* __restrict__ g,
    const float* __restrict__ bt, TO* __restrict__ y, float eps)
{
    int row = blockIdx.x, tid = threadIdx.x;
    long long base = (long long)row * 512;
    float v0 = ldany(&x[base + tid]);
    float v1 = ldany(&x[base + 256 + tid]);
    float s = v0 + v1, ss = v0 * v0 + v1 * v1;
    #pragma unroll
    for (int o = 32; o >= 1; o >>= 1) { s += __shfl_xor(s, o); ss += __shfl_xor(ss, o); }
    __shared__ float red[2][4];
    int wave = tid >> 6, lane = tid & 63;
    if (lane == 0) { red[0][wave] = s; red[1][wave] = ss; }
    __syncthreads();
    s  = red[0][0] + red[0][1] + red[0][2] + red[0][3];
    ss = red[1][0] + red[1][1] + red[1][2] + red[1][3];
    float mean = s * (1.f / 512.f);
    float var = ss * (1.f / 512.f) - mean * mean;
    float rstd = rsqrtf(fmaxf(var, 0.f) + eps);
    float o0 = (v0 - mean) * rstd * g[tid]       + bt[tid];
    float o1 = (v1 - mean) * rstd * g[256 + tid] + bt[256 + tid];
    if constexpr (sizeof(TO) == 4) { y[base + tid] = o0; y[base + 256 + tid] = o1; }
    else { y[base + tid] = f2bs(o0); y[base + 256 + tid] = f2bs(o1); }
}

// ===========================================================================
// MoE expert attention v4: block = (expert e, batch b), thread = query s.
// Reads pre-projected q_e [3,16384,64]; K/V fp32 staged to LDS (broadcast
// reads, conflict-free). Two-pass softmax over R=32 entirely in registers.
// Fuses the gate: writes geo[row, e*64+d] = gate_e(row) * eo_e[row,d], so the
// gated combine collapses into ONE gemm: priori = geo[16384,192] @ Wo_cat,
// where Wo_cat is Wo_e [3,64,64] flattened row-major (= [192,64]).
// ===========================================================================
__global__ __launch_bounds__(128) void moe_attn_k(
    const float* __restrict__ qe,   // [3, B*S, 64]
    const float* __restrict__ ke,   // [3, B*R, 64]
    const float* __restrict__ ve,   // [3, B*R, 64]
    const float* __restrict__ xs,   // [B*S, 64] (for the gate)
    const float* __restrict__ Wg,   // [64,3]
    const float* __restrict__ bg,   // [3]
    float* __restrict__ geo)        // [B*S, 192]
{
    int e = blockIdx.x, b = blockIdx.y;
    int tid = threadIdx.x;
    __shared__ __align__(16) float kS[RR][64];
    __shared__ __align__(16) float vS[RR][64];

    {   // stage K/V tile for (e,b): 2048 floats each = 512 float4, coalesced
        const float4* ks = (const float4*)&ke[((long long)e * (BBt * RR) + (long long)b * RR) * 64];
        const float4* vs = (const float4*)&ve[((long long)e * (BBt * RR) + (long long)b * RR) * 64];
        float4* kd = (float4*)&kS[0][0];
        float4* vd = (float4*)&vS[0][0];
        #pragma unroll
        for (int t = 0; t < 4; ++t) {
            kd[tid + 128 * t] = ks[tid + 128 * t];
            vd[tid + 128 * t] = vs[tid + 128 * t];
        }
    }

    long long row = (long long)b * SS + tid;
    float q[64];
    {
        const float4* qp = (const float4*)&qe[((long long)e * (BBt * SS) + row) * 64];
        #pragma unroll
        for (int t = 0; t < 16; ++t) {
            float4 f = qp[t];
            q[4*t] = f.x; q[4*t+1] = f.y; q[4*t+2] = f.z; q[4*t+3] = f.w;
        }
    }

    // gate = softmax(xs_row @ Wg + bg)[e]
    float l0 = bg[0], l1 = bg[1], l2 = bg[2];
    {
        const float4* xr = (const float4*)&xs[row * 64];
        #pragma unroll
        for (int t = 0; t < 16; ++t) {
            float4 f = xr[t];
            float xv[4] = {f.x, f.y, f.z, f.w};
            #pragma unroll
            for (int u = 0; u < 4; ++u) {
                int j = 4 * t + u;
                l0 = fmaf(xv[u], Wg[j * 3 + 0], l0);
                l1 = fmaf(xv[u], Wg[j * 3 + 1], l1);
                l2 = fmaf(xv[u], Wg[j * 3 + 2], l2);
            }
        }
    }
    float mg = fmaxf(l0, fmaxf(l1, l2));
    float g0 = __expf(l0 - mg), g1 = __expf(l1 - mg), g2 = __expf(l2 - mg);
    float gate = (e == 0 ? g0 : (e == 1 ? g1 : g2)) / (g0 + g1 + g2);

    __syncthreads();

    // scores (two-pass softmax, all in registers)
    float s[RR];
    #pragma unroll
    for (int r = 0; r < RR; ++r) {
        float a0 = 0.f, a1 = 0.f, a2 = 0.f, a3 = 0.f;
        const float4* kr = (const float4*)&kS[r][0];
        #pragma unroll
        for (int t = 0; t < 16; ++t) {
            float4 f = kr[t];
            a0 = fmaf(q[4*t],   f.x, a0);
            a1 = fmaf(q[4*t+1], f.y, a1);
            a2 = fmaf(q[4*t+2], f.z, a2);
            a3 = fmaf(q[4*t+3], f.w, a3);
        }
        s[r] = ((a0 + a1) + (a2 + a3)) * 0.125f;   // 1/sqrt(64)
    }
    float m = s[0];
    #pragma unroll
    for (int r = 1; r < RR; ++r) m = fmaxf(m, s[r]);
    float l = 0.f;
    #pragma unroll
    for (int r = 0; r < RR; ++r) { s[r] = __expf(s[r] - m); l += s[r]; }
    float scale = gate / l;

    // PV
    float acc[64];
    #pragma unroll
    for (int d = 0; d < 64; ++d) acc[d] = 0.f;
    #pragma unroll
    for (int r = 0; r < RR; ++r) {
        float p = s[r];
        const float4* vr = (const float4*)&vS[r][0];
        #pragma unroll
        for (int t = 0; t < 16; ++t) {
            float4 f = vr[t];
            acc[4*t]   = fmaf(p, f.x, acc[4*t]);
            acc[4*t+1] = fmaf(p, f.y, acc[4*t+1]);
            acc[4*t+2] = fmaf(p, f.z, acc[4*t+2]);
            acc[4*t+3] = fmaf(p, f.w, acc[4*t+3]);
        }
    }
    float4* op = (float4*)&geo[row * 192 + e * 64];
    #pragma unroll
    for (int t = 0; t < 16; ++t) {
        float4 f;
        f.x = acc[4*t] * scale;   f.y = acc[4*t+1] * scale;
        f.z = acc[4*t+2] * scale; f.w = acc[4*t+3] * scale;
        op[t] = f;
    }
}

// ===========================================================================
// Small causal MHA on 64-dim priori (H=8, dh=8, S=128). qkv packed [B*S,192].
// ===========================================================================
__global__ __launch_bounds__(128) void attn_small_k(
    const float* __restrict__ qkv, float* __restrict__ out)
{
    int h = blockIdx.x, b = blockIdx.y;
    int tid = threadIdx.x;
    __shared__ float kS[SS][9], vS[SS][9];
    long long base = ((long long)b * SS + tid) * 192;
    #pragma unroll
    for (int d = 0; d < 8; ++d) {
        kS[tid][d] = qkv[base + 64 + h * 8 + d];
        vS[tid][d] = qkv[base + 128 + h * 8 + d];
    }
    float q[8];
    #pragma unroll
    for (int d = 0; d < 8; ++d)
        q[d] = qkv[base + h * 8 + d] * 0.35355339059327373f;
    __syncthreads();

    float m = -1e30f, l = 0.f, acc[8] = {};
    for (int j = 0; j <= tid; ++j) {
        float s = 0.f;
        #pragma unroll
        for (int d = 0; d < 8; ++d) s = fmaf(q[d], kS[j][d], s);
        float mn = fmaxf(m, s);
        float corr = __expf(m - mn);
        float p = __expf(s - mn);
        l = l * corr + p;
        #pragma unroll
        for (int d = 0; d < 8; ++d) acc[d] = fmaf(p, vS[j][d], acc[d] * corr);
        m = mn;
    }
    float inv = 1.f / l;
    #pragma unroll
    for (int d = 0; d < 8; ++d)
        out[((long long)b * SS + tid) * 64 + h * 8 + d] = acc[d] * inv;
}

__global__ __launch_bounds__(256) void ln64_k(
    const float* __restrict__ x, const float* __restrict__ g,
    const float* __restrict__ bt, float* __restrict__ y, int M)
{
    int wave = threadIdx.x >> 6, lane = threadIdx.x & 63;
    int row = blockIdx.x * 4 + wave;
    if (row >= M) return;
    long long base = (long long)row * 64;
    float v = x[base + lane];
    float s = v, ss = v * v;
    #pragma unroll
    for (int o = 32; o >= 1; o >>= 1) { s += __shfl_xor(s, o); ss += __shfl_xor(ss, o); }
    float mean = s * (1.f / 64.f);
    float var = ss * (1.f / 64.f) - mean * mean;
    float rstd = rsqrtf(fmaxf(var, 0.f) + 1e-5f);
    y[base + lane] = (v - mean) * rstd * g[lane] + bt[lane];
}

// ===========================================================================
extern "C" void kernel_launch(void* const* d_in, const int* in_sizes, int n_in,
                              void* d_out, int out_size, void* d_ws, size_t ws_size,
                              hipStream_t stream)
{
    (void)in_sizes; (void)n_in; (void)out_size; (void)ws_size;
    const float* hidden = (const float*)d_in[0];
    const float* tag    = (const float*)d_in[1];
    const float* feats  = (const float*)d_in[2];
    const float* refs   = (const float*)d_in[3];
    const float* W_moe  = (const float*)d_in[4];
    const float* b_moe  = (const float*)d_in[5];
    const float* Wg     = (const float*)d_in[6];
    const float* bg     = (const float*)d_in[7];
    const float* Wq_e   = (const float*)d_in[8];
    const float* Wk_e   = (const float*)d_in[9];
    const float* Wv_e   = (const float*)d_in[10];
    const float* Wo_e   = (const float*)d_in[11];
    const float* g_np   = (const float*)d_in[12];
    const float* b_np   = (const float*)d_in[13];
    const float* Wi_p   = (const float*)d_in[14];
    const float* bi_p   = (const float*)d_in[15];
    const float* Wo_p   = (const float*)d_in[16];
    const float* bo_p   = (const float*)d_in[17];
    const float* W_pe   = (const float*)d_in[18];
    const float* b_pe   = (const float*)d_in[19];
    const float* g_nh   = (const float*)d_in[20];
    const float* b_nh   = (const float*)d_in[21];
    const float* Wi_f   = (const float*)d_in[22];
    const float* bi_f   = (const float*)d_in[23];
    const float* Wo_f   = (const float*)d_in[24];
    const float* bo_f   = (const float*)d_in[25];
    const float* g_nfh  = (const float*)d_in[26];
    const float* b_nfh  = (const float*)d_in[27];
    const float* Wq_a   = (const float*)d_in[28];
    const float* bq_a   = (const float*)d_in[29];
    const float* Wk_a   = (const float*)d_in[30];
    const float* bk_a   = (const float*)d_in[31];
    const float* Wv_a   = (const float*)d_in[32];
    const float* bv_a   = (const float*)d_in[33];
    const float* Wd     = (const float*)d_in[34];
    const float* bd     = (const float*)d_in[35];
    const float* g_ln   = (const float*)d_in[36];
    const float* b_ln   = (const float*)d_in[37];
    float* out = (float*)d_out;
    char* ob = (char*)d_out;
    char* wb = (char*)d_ws;

    // bf16 slabs: ws = W0|W1 (16 MiB each); d_out doubles as O0|O1.
    u16* W0 = (u16*)(wb + 0LL * 16 * MB);
    u16* W1 = (u16*)(wb + 1LL * 16 * MB);
    u16* O0 = (u16*)(ob + 0LL * 16 * MB);
    u16* O1 = (u16*)(ob + 1LL * 16 * MB);

    // Stage A fp32 scratch: in d_out (lifetime-disjoint with O0/O1 use) and
    // in ws (o_qe under W0's slab, o_geo under W1's slab — both dead before
    // W0/W1 are first written in stages B/C).
    float* o_xs   = (float*)(ob + 0LL  * MB);
    float* o_ke   = (float*)(ob + 4LL  * MB);
    float* o_ve   = (float*)(ob + 7LL  * MB);
    float* o_pri  = (float*)(ob + 10LL * MB);
    float* o_np64 = (float*)(ob + 14LL * MB);
    float* o_qkv  = (float*)(ob + 18LL * MB);
    float* o_attp = (float*)(ob + 0LL  * MB);
    float* o_tmp  = (float*)(ob + 4LL  * MB);
    float* o_qe   = (float*)(wb + 0LL  * MB);   // [3,16384,64] = 12 MiB
    float* o_geo  = (float*)(wb + 16LL * MB);   // [16384,192]  = 12.6 MiB

    dim3 blk(256);
    const float* fnull = nullptr;

    // ---- A: MoE priori (decomposed: GEMM q_e -> batched attn+gate -> GEMM) ----
    gemm_mfma<float, float, float><<<dim3(1, 128), blk, 0, stream>>>(     // xs
        tag, 512, 0, W_moe, 64, 0, b_moe, fnull, 0, o_xs, 64, 0, 512, 64);
    gemm_mfma<float, float, float><<<dim3(1, 32, 3), blk, 0, stream>>>(   // k_e
        refs, 512, 4096LL * 512, Wk_e, 64, 512LL * 64, nullptr, fnull, 0,
        o_ke, 64, 4096LL * 64, 512, 64);
    gemm_mfma<float, float, float><<<dim3(1, 32, 3), blk, 0, stream>>>(   // v_e
        refs, 512, 4096LL * 512, Wv_e, 64, 512LL * 64, nullptr, fnull, 0,
        o_ve, 64, 4096LL * 64, 512, 64);
    gemm_mfma<float, float, float><<<dim3(1, 128, 3), blk, 0, stream>>>(  // q_e
        o_xs, 64, 0, Wq_e, 64, 4096LL, nullptr, fnull, 0,
        o_qe, 64, 16384LL * 64, 64, 64);
    moe_attn_k<<<dim3(3, 128), dim3(128), 0, stream>>>(                   // geo = gate*eo
        o_qe, o_ke, o_ve, o_xs, Wg, bg, o_geo);
    gemm_mfma<float, float, float><<<dim3(1, 128), blk, 0, stream>>>(     // priori = geo @ Wo_cat
        o_geo, 192, 0, Wo_e, 64, 0, nullptr, fnull, 0, o_pri, 64, 0, 192, 64);

    // ---- B: priori causal self-MHA + expansion to 512 ----
    ln64_k<<<dim3(4096), blk, 0, stream>>>(o_pri, g_np, b_np, o_np64, 16384);
    gemm_mfma<float, float, float><<<dim3(2, 128), blk, 0, stream>>>(     // qkv_p
        o_np64, 64, 0, Wi_p, 192, 0, bi_p, fnull, 0, o_qkv, 192, 0, 64, 192);
    attn_small_k<<<dim3(8, 128), dim3(128), 0, stream>>>(o_qkv, o_attp);
    gemm_mfma<float, float, float><<<dim3(1, 128), blk, 0, stream>>>(     // tmp64
        o_attp, 64, 0, Wo_p, 64, 0, bo_p, o_pri, 64, o_tmp, 64, 0, 64, 64);
    gemm_mfma<float, float, u16><<<dim3(4, 128), blk, 0, stream>>>(       // priori_e -> W0
        o_tmp, 64, 0, W_pe, 512, 0, b_pe, fnull, 0, W0, 512, 0, 64, 512);

    // ---- C: fusion cross-MHA ----
    ln512_t<u16, u16><<<dim3(16384), blk, 0, stream>>>(W0, g_nh, b_nh, W0, 1e-5f); // npri
    gemm_mfma<u16, float, u16><<<dim3(4, 128), blk, 0, stream>>>(                   // Kf -> O1
        W0, 512, 0, Wi_f + 512, 1536, 0, bi_f + 512, fnull, 0, O1, 512, 0, 512, 512);
    gemm_mfma<u16, float, u16><<<dim3(4, 128), blk, 0, stream>>>(                   // Vf -> W1
        W0, 512, 0, Wi_f + 1024, 1536, 0, bi_f + 1024, fnull, 0, W1, 512, 0, 512, 512);
    gemm_mfma<float, float, u16><<<dim3(4, 128), blk, 0, stream>>>(                 // Qf -> O0
        hidden, 512, 0, Wi_f, 1536, 0, bi_f, fnull, 0, O0, 512, 0, 512, 512);
    attn_mfma_k<<<dim3(8, 128), dim3(256), 0, stream>>>(O0, O1, W1, W0, 128, 1);    // attn -> W0
    gemm_mfma<u16, float, u16><<<dim3(4, 128), blk, 0, stream>>>(                   // hidden2 -> O0
        W0, 512, 0, Wo_f, 512, 0, bo_f, hidden, 512, O0, 512, 0, 512, 512);

    // ---- D: feat cross-attention ----
    ln512_t<u16, u16><<<dim3(16384), blk, 0, stream>>>(O0, g_nfh, b_nfh, O0, 1e-5f); // nh
    gemm_mfma<u16, float, u16><<<dim3(4, 128), blk, 0, stream>>>(                    // q_a -> O1
        O0, 512, 0, Wq_a, 512, 0, bq_a, fnull, 0, O1, 512, 0, 512, 512);
    gemm_mfma<float, float, u16><<<dim3(4, 84), blk, 0, stream>>>(                   // k_a -> W0
        feats, 512, 0, Wk_a, 512, 0, bk_a, fnull, 0, W0, 512, 0, 512, 512);
    gemm_mfma<float, float, u16><<<dim3(4, 84), blk, 0, stream>>>(                   // v_a -> W1
        feats, 512, 0, Wv_a, 512, 0, bv_a, fnull, 0, W1, 512, 0, 512, 512);
    attn_mfma_k<<<dim3(8, 128), dim3(256), 0, stream>>>(O1, W0, W1, O1, 84, 0);      // ctx in-place
    gemm_mfma<u16, u16, u16><<<dim3(4, 128), blk, 0, stream>>>(                      // ctxd -> W0
        O1, 512, 0, Wd, 512, 0, bd, O0, 512, W0, 512, 0, 512, 512);

    // ---- E: final post-LN (eps=1e-12) -> fp32 d_out ----
    ln512_t<u16, float><<<dim3(16384), blk, 0, stream>>>(W0, g_ln, b_ln, out, 1e-12f);
}